// Round 1
// 178.483 us; speedup vs baseline: 1.2772x; 1.2772x over previous
//
#include <hip/hip_runtime.h>

typedef float f32x4 __attribute__((ext_vector_type(4)));
typedef float f32x16 __attribute__((ext_vector_type(16)));
typedef __bf16 bf16x4 __attribute__((ext_vector_type(4)));
typedef __bf16 bf16x8 __attribute__((ext_vector_type(8)));

constexpr int E = 1024;   // embed dim = K for all GEMMs
constexpr int S = 2048;   // sequence length
constexpr int Bsz = 2;    // batch
constexpr int H = 16;     // heads
constexpr int Dh = 64;    // head dim
constexpr int M = Bsz * S; // 4096 rows for projection GEMMs

#define GLOAD_LDS16(g, l)                                                                 \
  __builtin_amdgcn_global_load_lds((const __attribute__((address_space(1))) void*)(g),    \
                                   (__attribute__((address_space(3))) void*)(l), 16, 0, 0)

__device__ __forceinline__ unsigned pk2(float a, float b) {
  union { __bf16 h[2]; unsigned u; } r;
  r.h[0] = (__bf16)a; r.h[1] = (__bf16)b;
  return r.u;
}

// ---------------------------------------------------------------------------
// NT GEMM: C[m,n] = sum_k A[m,k] * Bw[n,k]
// MODE 2: out fp32, layout [M,N] (final output GEMM). TM = tile rows.
// ---------------------------------------------------------------------------
template <int MODE, typename AT, int TM>
__global__ __launch_bounds__(256) void gemm_nt(const AT* __restrict__ A,
                                               const float* __restrict__ Bw,
                                               void* __restrict__ Cout,
                                               float scale) {
  constexpr int MI = TM / 32;          // 16-row fragments per wave (m dir)
  __shared__ __bf16 As[TM][72];
  __shared__ __bf16 Bs[128][72];

  const int t    = threadIdx.x;
  const int lane = t & 63;
  const int wid  = t >> 6;
  const int wr   = (wid >> 1) * (TM / 2);
  const int wc   = (wid & 1) * 64;
  const int r16  = lane & 15;
  const int g8   = (lane >> 4) * 8;
  const int tm   = blockIdx.y * TM;
  const int tn   = blockIdx.x * 128;

  f32x4 acc[MI][4] = {};

  for (int kt = 0; kt < E / 64; ++kt) {
    const int k0 = kt * 64;
    __syncthreads();
    if constexpr (sizeof(AT) == 4) {
#pragma unroll
      for (int i = 0; i < TM / 16; ++i) {
        int c = t + i * 256;
        int row = c >> 4;
        int col = (c & 15) * 4;
        f32x4 v = *reinterpret_cast<const f32x4*>(&A[(size_t)(tm + row) * E + k0 + col]);
        bf16x4 hv;
        hv[0] = (__bf16)v[0]; hv[1] = (__bf16)v[1];
        hv[2] = (__bf16)v[2]; hv[3] = (__bf16)v[3];
        *reinterpret_cast<bf16x4*>(&As[row][col]) = hv;
      }
    } else {
#pragma unroll
      for (int i = 0; i < TM / 32; ++i) {
        int c = t + i * 256;
        int row = c >> 3;
        int col = (c & 7) * 8;
        *reinterpret_cast<bf16x8*>(&As[row][col]) =
            *reinterpret_cast<const bf16x8*>(&A[(size_t)(tm + row) * E + k0 + col]);
      }
    }
#pragma unroll
    for (int i = 0; i < 8; ++i) {
      int c = t + i * 256;
      int row = c >> 4;
      int col = (c & 15) * 4;
      f32x4 v = *reinterpret_cast<const f32x4*>(&Bw[(size_t)(tn + row) * E + k0 + col]);
      bf16x4 hv;
      hv[0] = (__bf16)v[0]; hv[1] = (__bf16)v[1];
      hv[2] = (__bf16)v[2]; hv[3] = (__bf16)v[3];
      *reinterpret_cast<bf16x4*>(&Bs[row][col]) = hv;
    }
    __syncthreads();
#pragma unroll
    for (int kc = 0; kc < 2; ++kc) {
      bf16x8 af[MI], bfv[4];
#pragma unroll
      for (int mi = 0; mi < MI; ++mi)
        af[mi] = *reinterpret_cast<const bf16x8*>(&As[wr + mi * 16 + r16][kc * 32 + g8]);
#pragma unroll
      for (int ni = 0; ni < 4; ++ni)
        bfv[ni] = *reinterpret_cast<const bf16x8*>(&Bs[wc + ni * 16 + r16][kc * 32 + g8]);
#pragma unroll
      for (int mi = 0; mi < MI; ++mi)
#pragma unroll
        for (int ni = 0; ni < 4; ++ni)
          acc[mi][ni] = __builtin_amdgcn_mfma_f32_16x16x32_bf16(af[mi], bfv[ni],
                                                                acc[mi][ni], 0, 0, 0);
    }
  }

#pragma unroll
  for (int mi = 0; mi < MI; ++mi) {
#pragma unroll
    for (int ni = 0; ni < 4; ++ni) {
#pragma unroll
      for (int j = 0; j < 4; ++j) {
        float v = acc[mi][ni][j] * scale;
        int m = tm + wr + mi * 16 + ((lane >> 4) << 2) + j;
        int n = tn + wc + ni * 16 + r16;
        ((float*)Cout)[(size_t)m * E + n] = v;
      }
    }
  }
}

// ---------------------------------------------------------------------------
// Merged Q/K/V projection: one launch, grid.z picks {Q,K,V}. 3 blocks/CU.
// z=0: qb [B,H,S,D] bf16, scale 1/8;  z=1: kb [B,H,S,D];  z=2: vtb [B,H,D,S].
// ---------------------------------------------------------------------------
__global__ __launch_bounds__(256) void proj_gemm(const float* __restrict__ Aq,
                                                 const float* __restrict__ Ak,
                                                 const float* __restrict__ Av,
                                                 const float* __restrict__ Wq,
                                                 const float* __restrict__ Wk,
                                                 const float* __restrict__ Wv,
                                                 __bf16* __restrict__ qb,
                                                 __bf16* __restrict__ kb,
                                                 __bf16* __restrict__ vtb) {
  __shared__ __bf16 As[128][72];
  __shared__ __bf16 Bs[128][72];

  const int which = blockIdx.z;
  const float* A  = which == 0 ? Aq : which == 1 ? Ak : Av;
  const float* Bw = which == 0 ? Wq : which == 1 ? Wk : Wv;
  __bf16* Cout    = which == 0 ? qb : which == 1 ? kb : vtb;
  const float scale = which == 0 ? 0.125f : 1.0f;

  const int t    = threadIdx.x;
  const int lane = t & 63;
  const int wid  = t >> 6;
  const int wr   = (wid >> 1) * 64;
  const int wc   = (wid & 1) * 64;
  const int r16  = lane & 15;
  const int g8   = (lane >> 4) * 8;
  const int tm   = blockIdx.y * 128;
  const int tn   = blockIdx.x * 128;

  f32x4 acc[4][4] = {};

  for (int kt = 0; kt < E / 64; ++kt) {
    const int k0 = kt * 64;
    __syncthreads();
#pragma unroll
    for (int i = 0; i < 8; ++i) {
      int c = t + i * 256;
      int row = c >> 4;
      int col = (c & 15) * 4;
      f32x4 va = *reinterpret_cast<const f32x4*>(&A[(size_t)(tm + row) * E + k0 + col]);
      f32x4 vb = *reinterpret_cast<const f32x4*>(&Bw[(size_t)(tn + row) * E + k0 + col]);
      bf16x4 ha, hb;
      ha[0] = (__bf16)va[0]; ha[1] = (__bf16)va[1];
      ha[2] = (__bf16)va[2]; ha[3] = (__bf16)va[3];
      hb[0] = (__bf16)vb[0]; hb[1] = (__bf16)vb[1];
      hb[2] = (__bf16)vb[2]; hb[3] = (__bf16)vb[3];
      *reinterpret_cast<bf16x4*>(&As[row][col]) = ha;
      *reinterpret_cast<bf16x4*>(&Bs[row][col]) = hb;
    }
    __syncthreads();
#pragma unroll
    for (int kc = 0; kc < 2; ++kc) {
      bf16x8 af[4], bfv[4];
#pragma unroll
      for (int mi = 0; mi < 4; ++mi)
        af[mi] = *reinterpret_cast<const bf16x8*>(&As[wr + mi * 16 + r16][kc * 32 + g8]);
#pragma unroll
      for (int ni = 0; ni < 4; ++ni)
        bfv[ni] = *reinterpret_cast<const bf16x8*>(&Bs[wc + ni * 16 + r16][kc * 32 + g8]);
#pragma unroll
      for (int mi = 0; mi < 4; ++mi)
#pragma unroll
        for (int ni = 0; ni < 4; ++ni)
          acc[mi][ni] = __builtin_amdgcn_mfma_f32_16x16x32_bf16(af[mi], bfv[ni],
                                                                acc[mi][ni], 0, 0, 0);
    }
  }

#pragma unroll
  for (int mi = 0; mi < 4; ++mi) {
#pragma unroll
    for (int ni = 0; ni < 4; ++ni) {
#pragma unroll
      for (int j = 0; j < 4; ++j) {
        float v = acc[mi][ni][j] * scale;
        int m = tm + wr + mi * 16 + ((lane >> 4) << 2) + j;
        int n = tn + wc + ni * 16 + r16;
        int b = m >> 11, s = m & 2047, h = n >> 6, d = n & 63;
        if (which < 2) {
          Cout[((size_t)(b * H + h) * S + s) * Dh + d] = (__bf16)v;
        } else {
          Cout[((size_t)(b * H + h) * Dh + d) * S + s] = (__bf16)v;
        }
      }
    }
  }
}

// ---------------------------------------------------------------------------
// Sigmoid attention, swapped-operand 32x32x16 MFMA, P never touches LDS.
// Per block: 128 q-rows, head h, batch b. 4 waves x 32 q-rows. KV tile = 64.
//   St = mfma(Kfrag, Qfrag)  -> St[s][q], col q = lane&31 (q stays lane-local)
//   sigmoid in-register; PV B-frags built with 4 shfl_xor(32) per 32x32 tile
//   Ot[d][q] = mfma(Vtfrag, Pfrag); transposed via LDS at epilogue.
// K/V staged via global_load_lds w=16, XOR-swizzled source (linear LDS dest).
// ---------------------------------------------------------------------------
__global__ __launch_bounds__(256) void attn_sigmoid(const __bf16* __restrict__ Q,
                                                    const __bf16* __restrict__ K,
                                                    const __bf16* __restrict__ Vt,
                                                    __bf16* __restrict__ O) {
  __shared__ char smem[128 * 72 * 2];          // 18432 B
  __bf16* Ks = (__bf16*)smem;                  // [64][64] swizzled, 8 KB
  __bf16* Vs = (__bf16*)(smem + 8192);         // [64][64] swizzled (row=d), 8 KB
  __bf16* Os = (__bf16*)smem;                  // epilogue alias: [128][72]

  const int t    = threadIdx.x;
  const int lane = t & 63;
  const int wid  = t >> 6;
  const int l31  = lane & 31;
  const int hh   = lane >> 5;                  // wave half
  const int q0   = blockIdx.x * 128;
  const int h    = blockIdx.y;
  const int b    = blockIdx.z;

  const __bf16* Qh = Q + (size_t)(b * H + h) * S * Dh;
  const __bf16* Kh = K + (size_t)(b * H + h) * S * Dh;
  const __bf16* Vh = Vt + (size_t)(b * H + h) * Dh * S;

  // hoisted Q fragments (B-operand): Qf[kc] = Q[q0+wid*32+l31][kc*16 + hh*8 + 0..7]
  bf16x8 Qf[4];
#pragma unroll
  for (int kc = 0; kc < 4; ++kc)
    Qf[kc] = *reinterpret_cast<const bf16x8*>(
        &Qh[(size_t)(q0 + wid * 32 + l31) * Dh + kc * 16 + hh * 8]);

  f32x16 ot[2] = {};   // Ot[d][q]: d blocks of 32, q = this wave's 32 cols

  for (int st = 0; st < S / 64; ++st) {
    __syncthreads();   // previous iteration's readers done
    // stage K,V tiles: LDS[row][x] <- G[row][x ^ (row&7)]  (16B granules)
#pragma unroll
    for (int j = 0; j < 2; ++j) {
      int base = (wid * 2 + j) * 1024;         // bytes; wave-uniform LDS dest
      int L    = base + lane * 16;
      int row  = L >> 7;                       // 128 B per row
      int x    = (L >> 4) & 7;
      int sw   = ((x ^ (row & 7)) * 8);        // element offset in row
      GLOAD_LDS16(&Kh[(size_t)(st * 64 + row) * Dh + sw], (char*)Ks + base);
      GLOAD_LDS16(&Vh[(size_t)row * S + st * 64 + sw], (char*)Vs + base);
    }
    __syncthreads();   // drains vmcnt: tiles ready

#pragma unroll
    for (int si = 0; si < 2; ++si) {
      // ---- St = K Q^T (swapped): St[s_local][q], s_local = si*32 .. +31 ----
      f32x16 sacc = {};
#pragma unroll
      for (int kc = 0; kc < 4; ++kc) {
        int row = si * 32 + l31;
        int x = (2 * kc + hh) ^ (row & 7);
        bf16x8 kf = *reinterpret_cast<const bf16x8*>(&Ks[row * 64 + x * 8]);
        sacc = __builtin_amdgcn_mfma_f32_32x32x16_bf16(kf, Qf[kc], sacc, 0, 0, 0);
      }
      // ---- sigmoid in-register; lane holds P[q = lane&31][32 s values] ----
      float p[16];
#pragma unroll
      for (int r = 0; r < 16; ++r)
        p[r] = __builtin_amdgcn_rcpf(1.0f + __expf(-sacc[r]));
      // reg r -> s_local(32) = (r&3) + 8*(r>>2) + 4*hh
      unsigned A0 = pk2(p[0], p[1]),   A1 = pk2(p[2], p[3]);    // s = 4hh+{0..3}
      unsigned B0 = pk2(p[4], p[5]),   B1 = pk2(p[6], p[7]);    // s = 8+4hh+{0..3}
      unsigned C0 = pk2(p[8], p[9]),   C1 = pk2(p[10], p[11]);  // s = 16+4hh+{..}
      unsigned D0 = pk2(p[12], p[13]), D1 = pk2(p[14], p[15]);  // s = 24+4hh+{..}
      // each half offers what the other half needs; one xor-32 swap serves both
      unsigned W0 = __shfl_xor((int)(hh ? A0 : B0), 32, 64);
      unsigned W1 = __shfl_xor((int)(hh ? A1 : B1), 32, 64);
      unsigned W2 = __shfl_xor((int)(hh ? C0 : D0), 32, 64);
      unsigned W3 = __shfl_xor((int)(hh ? C1 : D1), 32, 64);
      union { unsigned u[4]; bf16x8 v; } f0, f1;
      f0.u[0] = hh ? W0 : A0;  f0.u[1] = hh ? W1 : A1;   // chunk si*2:   s_loc 0..15
      f0.u[2] = hh ? B0 : W0;  f0.u[3] = hh ? B1 : W1;
      f1.u[0] = hh ? W2 : C0;  f1.u[1] = hh ? W3 : C1;   // chunk si*2+1: s_loc 16..31
      f1.u[2] = hh ? D0 : W2;  f1.u[3] = hh ? D1 : W3;

      // ---- Ot[d][q] += Vt P: A = Vt[d][s] frag, B = P frag ----
#pragma unroll
      for (int dblk = 0; dblk < 2; ++dblk) {
        int row = dblk * 32 + l31;
        int c0 = si * 2;
        int x0 = (2 * c0 + hh) ^ (row & 7);
        int x1 = (2 * (c0 + 1) + hh) ^ (row & 7);
        bf16x8 vf0 = *reinterpret_cast<const bf16x8*>(&Vs[row * 64 + x0 * 8]);
        bf16x8 vf1 = *reinterpret_cast<const bf16x8*>(&Vs[row * 64 + x1 * 8]);
        ot[dblk] = __builtin_amdgcn_mfma_f32_32x32x16_bf16(vf0, f0.v, ot[dblk], 0, 0, 0);
        ot[dblk] = __builtin_amdgcn_mfma_f32_32x32x16_bf16(vf1, f1.v, ot[dblk], 0, 0, 0);
      }
    }
  }

  // ---- epilogue: transpose Ot through LDS, coalesced bf16x8 global stores ----
  __syncthreads();   // Ks/Vs dead; alias as Os[128][72]
#pragma unroll
  for (int dblk = 0; dblk < 2; ++dblk) {
#pragma unroll
    for (int rp = 0; rp < 8; ++rp) {
      int r = rp * 2;
      int d0 = dblk * 32 + (r & 3) + 8 * (r >> 2) + 4 * hh;   // d0 even, pair d0,d0+1
      unsigned u = pk2(ot[dblk][r], ot[dblk][r + 1]);
      *reinterpret_cast<unsigned*>(&Os[(wid * 32 + l31) * 72 + d0]) = u;
    }
  }
  __syncthreads();
#pragma unroll
  for (int i = 0; i < 4; ++i) {
    int c = i * 256 + t;
    int row = c >> 3;
    int ch = c & 7;
    bf16x8 v = *reinterpret_cast<const bf16x8*>(&Os[row * 72 + ch * 8]);
    *reinterpret_cast<bf16x8*>(&O[((size_t)(b * S) + q0 + row) * E + h * Dh + ch * 8]) = v;
  }
}

extern "C" void kernel_launch(void* const* d_in, const int* in_sizes, int n_in,
                              void* d_out, int out_size, void* d_ws, size_t ws_size,
                              hipStream_t stream) {
  const float* query = (const float*)d_in[0];
  const float* key_  = (const float*)d_in[1];
  const float* value = (const float*)d_in[2];
  const float* Wq    = (const float*)d_in[3];
  const float* Wk    = (const float*)d_in[4];
  const float* Wv    = (const float*)d_in[5];
  const float* Wo    = (const float*)d_in[6];

  char* ws = (char*)d_ws;
  __bf16* qb  = (__bf16*)(ws);                          // [B,H,S,D] bf16, 8 MB
  __bf16* kb  = (__bf16*)(ws + ((size_t)8 << 20));      // [B,H,S,D]
  __bf16* vtb = (__bf16*)(ws + ((size_t)16 << 20));     // [B,H,D,S]
  __bf16* ob  = (__bf16*)(ws + ((size_t)24 << 20));     // [M,E]

  // merged Q/K/V projections: 768 blocks -> 3 blocks/CU
  proj_gemm<<<dim3(E / 128, M / 128, 3), 256, 0, stream>>>(
      query, key_, value, Wq, Wk, Wv, qb, kb, vtb);

  attn_sigmoid<<<dim3(S / 128, H, Bsz), 256, 0, stream>>>(qb, kb, vtb, ob);

  // final GEMM: 64-row tiles -> 512 blocks -> 2 blocks/CU
  gemm_nt<2, __bf16, 64><<<dim3(E / 128, M / 64), 256, 0, stream>>>(
      ob, Wo, (float*)d_out, 1.0f);
}

// Round 2
// 160.111 us; speedup vs baseline: 1.4238x; 1.1147x over previous
//
#include <hip/hip_runtime.h>

typedef float f32x4 __attribute__((ext_vector_type(4)));
typedef float f32x16 __attribute__((ext_vector_type(16)));
typedef __bf16 bf16x4 __attribute__((ext_vector_type(4)));
typedef __bf16 bf16x8 __attribute__((ext_vector_type(8)));

constexpr int E = 1024;   // embed dim = K for all GEMMs
constexpr int S = 2048;   // sequence length
constexpr int Bsz = 2;    // batch
constexpr int H = 16;     // heads
constexpr int Dh = 64;    // head dim
constexpr int M = Bsz * S; // 4096 rows for projection GEMMs

#define GLOAD_LDS16(g, l)                                                                 \
  __builtin_amdgcn_global_load_lds((const __attribute__((address_space(1))) void*)(g),    \
                                   (__attribute__((address_space(3))) void*)(l), 16, 0, 0)

__device__ __forceinline__ unsigned pk2(float a, float b) {
  union { __bf16 h[2]; unsigned u; } r;
  r.h[0] = (__bf16)a; r.h[1] = (__bf16)b;
  return r.u;
}

// ---------------------------------------------------------------------------
// fp32 -> bf16 convert pass. blockIdx.y picks tensor:
// 0..2: query/key/value [M,E];  3..5: Wq*0.125 / Wk / Wv -> Wqkv[3][E][E];
// 6: Wo -> Wob.
// ---------------------------------------------------------------------------
__global__ __launch_bounds__(256) void convert_bf16(
    const float* __restrict__ q, const float* __restrict__ k,
    const float* __restrict__ v, const float* __restrict__ wq,
    const float* __restrict__ wk, const float* __restrict__ wv,
    const float* __restrict__ wo, __bf16* __restrict__ aq,
    __bf16* __restrict__ ak, __bf16* __restrict__ av,
    __bf16* __restrict__ wqkv, __bf16* __restrict__ wob) {
  const int id = blockIdx.y;
  const float* src;
  __bf16* dst;
  int n;
  float scale = 1.0f;
  switch (id) {
    case 0: src = q;  dst = aq;             n = M * E; break;
    case 1: src = k;  dst = ak;             n = M * E; break;
    case 2: src = v;  dst = av;             n = M * E; break;
    case 3: src = wq; dst = wqkv;           n = E * E; scale = 0.125f; break;
    case 4: src = wk; dst = wqkv + E * E;   n = E * E; break;
    case 5: src = wv; dst = wqkv + 2 * E * E; n = E * E; break;
    default: src = wo; dst = wob;           n = E * E; break;
  }
  const int stride = gridDim.x * 256 * 8;
  for (int i = (blockIdx.x * 256 + threadIdx.x) * 8; i < n; i += stride) {
    f32x4 a = *reinterpret_cast<const f32x4*>(&src[i]);
    f32x4 b = *reinterpret_cast<const f32x4*>(&src[i + 4]);
    bf16x8 o;
    o[0] = (__bf16)(a[0] * scale); o[1] = (__bf16)(a[1] * scale);
    o[2] = (__bf16)(a[2] * scale); o[3] = (__bf16)(a[3] * scale);
    o[4] = (__bf16)(b[0] * scale); o[5] = (__bf16)(b[1] * scale);
    o[6] = (__bf16)(b[2] * scale); o[7] = (__bf16)(b[3] * scale);
    *reinterpret_cast<bf16x8*>(&dst[i]) = o;
  }
}

// ---------------------------------------------------------------------------
// bf16 NT GEMM, m97 structure: global_load_lds w=16 staging, linear LDS dest,
// XOR-swizzled source granules + swizzled ds_read (conflict-free).
// MODE 0: merged projection. n in [0,3072): which = n>>10 picks {Q,K,V};
//         out bf16 -> pq/pk [B,H,S,D], pvt [B,H,D,S].
// MODE 2: final GEMM, out fp32 [M,E].
// ---------------------------------------------------------------------------
template <int TM, int MODE>
__global__ __launch_bounds__(256) void gemm_bf16nt(
    const __bf16* __restrict__ A0, const __bf16* __restrict__ A1,
    const __bf16* __restrict__ A2, const __bf16* __restrict__ Bw,
    void* __restrict__ C0, void* __restrict__ C1, void* __restrict__ C2) {
  constexpr int MI = TM / 32;
  __shared__ __bf16 As[TM][64];
  __shared__ __bf16 Bs[128][64];

  const int t    = threadIdx.x;
  const int lane = t & 63;
  const int wid  = t >> 6;
  const int wr   = (wid >> 1) * (TM / 2);
  const int wc   = (wid & 1) * 64;
  const int r16  = lane & 15;
  const int tm   = blockIdx.y * TM;
  const int tn   = blockIdx.x * 128;
  const int which = tn >> 10;

  const __bf16* Ab = (MODE == 0) ? (which == 0 ? A0 : which == 1 ? A1 : A2) : A0;

  f32x4 acc[MI][4] = {};

  for (int kt = 0; kt < E / 64; ++kt) {
    const int k0 = kt * 64;
    __syncthreads();
    // ---- stage A [TM][64] + B [128][64] via global_load_lds (swizzled src) ----
    constexpr int ACH = TM / 8;        // 1 KB chunks in A tile
    constexpr int NCH = ACH + 16;
#pragma unroll
    for (int c = wid; c < NCH; c += 4) {
      const bool isA = c < ACH;
      const int cc   = isA ? c : c - ACH;
      const int L    = cc * 1024 + lane * 16;   // byte offset in tile
      const int row  = L >> 7;                  // 128 B per row
      const int sw   = ((L >> 4) & 7) ^ (row & 7);
      const __bf16* src = isA ? &Ab[(size_t)(tm + row) * E + k0 + sw * 8]
                              : &Bw[(size_t)(tn + row) * E + k0 + sw * 8];
      char* dst = (isA ? (char*)As : (char*)Bs) + cc * 1024;
      GLOAD_LDS16(src, dst);
    }
    __syncthreads();
    // ---- MFMA over BK=64, swizzled fragment reads ----
#pragma unroll
    for (int kc = 0; kc < 2; ++kc) {
      bf16x8 af[MI], bfv[4];
#pragma unroll
      for (int mi = 0; mi < MI; ++mi) {
        int row = wr + mi * 16 + r16;
        int g   = (kc * 4 + (lane >> 4)) ^ (row & 7);
        af[mi] = *reinterpret_cast<const bf16x8*>(&As[row][g * 8]);
      }
#pragma unroll
      for (int ni = 0; ni < 4; ++ni) {
        int row = wc + ni * 16 + r16;
        int g   = (kc * 4 + (lane >> 4)) ^ (row & 7);
        bfv[ni] = *reinterpret_cast<const bf16x8*>(&Bs[row][g * 8]);
      }
#pragma unroll
      for (int mi = 0; mi < MI; ++mi)
#pragma unroll
        for (int ni = 0; ni < 4; ++ni)
          acc[mi][ni] = __builtin_amdgcn_mfma_f32_16x16x32_bf16(af[mi], bfv[ni],
                                                                acc[mi][ni], 0, 0, 0);
    }
  }

  // ---- epilogue: C/D layout col=lane&15, row=(lane>>4)*4+j ----
#pragma unroll
  for (int mi = 0; mi < MI; ++mi) {
#pragma unroll
    for (int ni = 0; ni < 4; ++ni) {
#pragma unroll
      for (int j = 0; j < 4; ++j) {
        float v = acc[mi][ni][j];
        int m = tm + wr + mi * 16 + ((lane >> 4) << 2) + j;
        int n = tn + wc + ni * 16 + r16;
        if constexpr (MODE == 0) {
          int nl = n & 1023;
          int b = m >> 11, s = m & 2047, h = nl >> 6, d = nl & 63;
          __bf16* Cout = which == 0 ? (__bf16*)C0 : which == 1 ? (__bf16*)C1
                                                              : (__bf16*)C2;
          if (which < 2)
            Cout[((size_t)(b * H + h) * S + s) * Dh + d] = (__bf16)v;
          else
            Cout[((size_t)(b * H + h) * Dh + d) * S + s] = (__bf16)v;
        } else {
          ((float*)C0)[(size_t)m * E + n] = v;
        }
      }
    }
  }
}

// ---------------------------------------------------------------------------
// Sigmoid attention, swapped-operand 32x32x16 MFMA, P never touches LDS.
// (unchanged from previous round — verified)
// ---------------------------------------------------------------------------
__global__ __launch_bounds__(256) void attn_sigmoid(const __bf16* __restrict__ Q,
                                                    const __bf16* __restrict__ K,
                                                    const __bf16* __restrict__ Vt,
                                                    __bf16* __restrict__ O) {
  __shared__ char smem[128 * 72 * 2];          // 18432 B
  __bf16* Ks = (__bf16*)smem;                  // [64][64] swizzled, 8 KB
  __bf16* Vs = (__bf16*)(smem + 8192);         // [64][64] swizzled (row=d), 8 KB
  __bf16* Os = (__bf16*)smem;                  // epilogue alias: [128][72]

  const int t    = threadIdx.x;
  const int lane = t & 63;
  const int wid  = t >> 6;
  const int l31  = lane & 31;
  const int hh   = lane >> 5;                  // wave half
  const int q0   = blockIdx.x * 128;
  const int h    = blockIdx.y;
  const int b    = blockIdx.z;

  const __bf16* Qh = Q + (size_t)(b * H + h) * S * Dh;
  const __bf16* Kh = K + (size_t)(b * H + h) * S * Dh;
  const __bf16* Vh = Vt + (size_t)(b * H + h) * Dh * S;

  bf16x8 Qf[4];
#pragma unroll
  for (int kc = 0; kc < 4; ++kc)
    Qf[kc] = *reinterpret_cast<const bf16x8*>(
        &Qh[(size_t)(q0 + wid * 32 + l31) * Dh + kc * 16 + hh * 8]);

  f32x16 ot[2] = {};   // Ot[d][q]

  for (int st = 0; st < S / 64; ++st) {
    __syncthreads();
#pragma unroll
    for (int j = 0; j < 2; ++j) {
      int base = (wid * 2 + j) * 1024;
      int L    = base + lane * 16;
      int row  = L >> 7;
      int x    = (L >> 4) & 7;
      int sw   = ((x ^ (row & 7)) * 8);
      GLOAD_LDS16(&Kh[(size_t)(st * 64 + row) * Dh + sw], (char*)Ks + base);
      GLOAD_LDS16(&Vh[(size_t)row * S + st * 64 + sw], (char*)Vs + base);
    }
    __syncthreads();

#pragma unroll
    for (int si = 0; si < 2; ++si) {
      f32x16 sacc = {};
#pragma unroll
      for (int kc = 0; kc < 4; ++kc) {
        int row = si * 32 + l31;
        int x = (2 * kc + hh) ^ (row & 7);
        bf16x8 kf = *reinterpret_cast<const bf16x8*>(&Ks[row * 64 + x * 8]);
        sacc = __builtin_amdgcn_mfma_f32_32x32x16_bf16(kf, Qf[kc], sacc, 0, 0, 0);
      }
      float p[16];
#pragma unroll
      for (int r = 0; r < 16; ++r)
        p[r] = __builtin_amdgcn_rcpf(1.0f + __expf(-sacc[r]));
      unsigned A0 = pk2(p[0], p[1]),   A1 = pk2(p[2], p[3]);
      unsigned B0 = pk2(p[4], p[5]),   B1 = pk2(p[6], p[7]);
      unsigned C0 = pk2(p[8], p[9]),   C1 = pk2(p[10], p[11]);
      unsigned D0 = pk2(p[12], p[13]), D1 = pk2(p[14], p[15]);
      unsigned W0 = __shfl_xor((int)(hh ? A0 : B0), 32, 64);
      unsigned W1 = __shfl_xor((int)(hh ? A1 : B1), 32, 64);
      unsigned W2 = __shfl_xor((int)(hh ? C0 : D0), 32, 64);
      unsigned W3 = __shfl_xor((int)(hh ? C1 : D1), 32, 64);
      union { unsigned u[4]; bf16x8 v; } f0, f1;
      f0.u[0] = hh ? W0 : A0;  f0.u[1] = hh ? W1 : A1;
      f0.u[2] = hh ? B0 : W0;  f0.u[3] = hh ? B1 : W1;
      f1.u[0] = hh ? W2 : C0;  f1.u[1] = hh ? W3 : C1;
      f1.u[2] = hh ? D0 : W2;  f1.u[3] = hh ? D1 : W3;

#pragma unroll
      for (int dblk = 0; dblk < 2; ++dblk) {
        int row = dblk * 32 + l31;
        int c0 = si * 2;
        int x0 = (2 * c0 + hh) ^ (row & 7);
        int x1 = (2 * (c0 + 1) + hh) ^ (row & 7);
        bf16x8 vf0 = *reinterpret_cast<const bf16x8*>(&Vs[row * 64 + x0 * 8]);
        bf16x8 vf1 = *reinterpret_cast<const bf16x8*>(&Vs[row * 64 + x1 * 8]);
        ot[dblk] = __builtin_amdgcn_mfma_f32_32x32x16_bf16(vf0, f0.v, ot[dblk], 0, 0, 0);
        ot[dblk] = __builtin_amdgcn_mfma_f32_32x32x16_bf16(vf1, f1.v, ot[dblk], 0, 0, 0);
      }
    }
  }

  __syncthreads();
#pragma unroll
  for (int dblk = 0; dblk < 2; ++dblk) {
#pragma unroll
    for (int rp = 0; rp < 8; ++rp) {
      int r = rp * 2;
      int d0 = dblk * 32 + (r & 3) + 8 * (r >> 2) + 4 * hh;
      unsigned u = pk2(ot[dblk][r], ot[dblk][r + 1]);
      *reinterpret_cast<unsigned*>(&Os[(wid * 32 + l31) * 72 + d0]) = u;
    }
  }
  __syncthreads();
#pragma unroll
  for (int i = 0; i < 4; ++i) {
    int c = i * 256 + t;
    int row = c >> 3;
    int ch = c & 7;
    bf16x8 v = *reinterpret_cast<const bf16x8*>(&Os[row * 72 + ch * 8]);
    *reinterpret_cast<bf16x8*>(&O[((size_t)(b * S) + q0 + row) * E + h * Dh + ch * 8]) = v;
  }
}

extern "C" void kernel_launch(void* const* d_in, const int* in_sizes, int n_in,
                              void* d_out, int out_size, void* d_ws, size_t ws_size,
                              hipStream_t stream) {
  const float* query = (const float*)d_in[0];
  const float* key_  = (const float*)d_in[1];
  const float* value = (const float*)d_in[2];
  const float* Wq    = (const float*)d_in[3];
  const float* Wk    = (const float*)d_in[4];
  const float* Wv    = (const float*)d_in[5];
  const float* Wo    = (const float*)d_in[6];

  char* ws = (char*)d_ws;
  // layout (56 MB): act_q/k/v 24 MB | Wqkv 6 MB | Wob 2 MB | pq 8 | pk 8 | pvt 8
  __bf16* aq   = (__bf16*)(ws);                         // [M,E] bf16
  __bf16* ak   = (__bf16*)(ws + ((size_t)8 << 20));
  __bf16* av   = (__bf16*)(ws + ((size_t)16 << 20));
  __bf16* wqkv = (__bf16*)(ws + ((size_t)24 << 20));    // [3072,1024]
  __bf16* wob  = (__bf16*)(ws + ((size_t)30 << 20));    // [1024,1024]
  __bf16* pq   = (__bf16*)(ws + ((size_t)32 << 20));    // [B,H,S,D]
  __bf16* pk   = (__bf16*)(ws + ((size_t)40 << 20));    // [B,H,S,D]
  __bf16* pvt  = (__bf16*)(ws + ((size_t)48 << 20));    // [B,H,D,S]
  __bf16* ob   = (__bf16*)(ws);                         // [M,E] aliases dead act_q

  convert_bf16<<<dim3(512, 7), 256, 0, stream>>>(query, key_, value, Wq, Wk, Wv,
                                                 Wo, aq, ak, av, wqkv, wob);

  // merged QKV projection: C[4096,3072] over Wqkv, 768 blocks (3/CU)
  gemm_bf16nt<128, 0><<<dim3(3072 / 128, M / 128), 256, 0, stream>>>(
      aq, ak, av, wqkv, pq, pk, pvt);

  attn_sigmoid<<<dim3(S / 128, H, Bsz), 256, 0, stream>>>(pq, pk, pvt, ob);

  // final GEMM: 64-row tiles -> 512 blocks (2/CU)
  gemm_bf16nt<64, 2><<<dim3(E / 128, M / 64), 256, 0, stream>>>(
      ob, nullptr, nullptr, wob, (float*)d_out, nullptr, nullptr);
}

// Round 3
// 154.265 us; speedup vs baseline: 1.4777x; 1.0379x over previous
//
#include <hip/hip_runtime.h>

typedef float f32x4 __attribute__((ext_vector_type(4)));
typedef float f32x16 __attribute__((ext_vector_type(16)));
typedef __bf16 bf16x4 __attribute__((ext_vector_type(4)));
typedef __bf16 bf16x8 __attribute__((ext_vector_type(8)));

constexpr int E = 1024;   // embed dim = K for all GEMMs
constexpr int S = 2048;   // sequence length
constexpr int Bsz = 2;    // batch
constexpr int H = 16;     // heads
constexpr int Dh = 64;    // head dim
constexpr int M = Bsz * S; // 4096 rows for projection GEMMs

#define GLOAD_LDS16(g, l)                                                                 \
  __builtin_amdgcn_global_load_lds((const __attribute__((address_space(1))) void*)(g),    \
                                   (__attribute__((address_space(3))) void*)(l), 16, 0, 0)

__device__ __forceinline__ unsigned pk2(float a, float b) {
  union { __bf16 h[2]; unsigned u; } r;
  r.h[0] = (__bf16)a; r.h[1] = (__bf16)b;
  return r.u;
}

// ---------------------------------------------------------------------------
// fp32 -> bf16 convert pass. blockIdx.y picks tensor:
// 0..2: query/key/value [M,E];  3..5: Wq*(-0.125*log2e) / Wk / Wv -> Wqkv;
// 6: Wo -> Wob.  (Q scale folded so sigmoid = rcp(1 + exp2(qk)).)
// ---------------------------------------------------------------------------
__global__ __launch_bounds__(256) void convert_bf16(
    const float* __restrict__ q, const float* __restrict__ k,
    const float* __restrict__ v, const float* __restrict__ wq,
    const float* __restrict__ wk, const float* __restrict__ wv,
    const float* __restrict__ wo, __bf16* __restrict__ aq,
    __bf16* __restrict__ ak, __bf16* __restrict__ av,
    __bf16* __restrict__ wqkv, __bf16* __restrict__ wob) {
  const int id = blockIdx.y;
  const float* src;
  __bf16* dst;
  int n;
  float scale = 1.0f;
  switch (id) {
    case 0: src = q;  dst = aq;             n = M * E; break;
    case 1: src = k;  dst = ak;             n = M * E; break;
    case 2: src = v;  dst = av;             n = M * E; break;
    case 3: src = wq; dst = wqkv;           n = E * E; scale = -0.18033688f; break;
    case 4: src = wk; dst = wqkv + E * E;   n = E * E; break;
    case 5: src = wv; dst = wqkv + 2 * E * E; n = E * E; break;
    default: src = wo; dst = wob;           n = E * E; break;
  }
  const int stride = gridDim.x * 256 * 8;
  for (int i = (blockIdx.x * 256 + threadIdx.x) * 8; i < n; i += stride) {
    f32x4 a = *reinterpret_cast<const f32x4*>(&src[i]);
    f32x4 b = *reinterpret_cast<const f32x4*>(&src[i + 4]);
    bf16x8 o;
    o[0] = (__bf16)(a[0] * scale); o[1] = (__bf16)(a[1] * scale);
    o[2] = (__bf16)(a[2] * scale); o[3] = (__bf16)(a[3] * scale);
    o[4] = (__bf16)(b[0] * scale); o[5] = (__bf16)(b[1] * scale);
    o[6] = (__bf16)(b[2] * scale); o[7] = (__bf16)(b[3] * scale);
    *reinterpret_cast<bf16x8*>(&dst[i]) = o;
  }
}

// ---------------------------------------------------------------------------
// bf16 NT GEMM, m97 structure: global_load_lds w=16 staging, linear LDS dest,
// XOR-swizzled source granules + swizzled ds_read (conflict-free).
// MODE 0: merged projection. which = tn>>10 picks {Q,K,V}.
//         V output gets its s-index bits 2<->3 swapped (PV chunk order) so
//         the attention kernel needs no cross-lane P exchange.
// MODE 2: final GEMM, out fp32 [M,E].
// ---------------------------------------------------------------------------
template <int TM, int MODE>
__global__ __launch_bounds__(256) void gemm_bf16nt(
    const __bf16* __restrict__ A0, const __bf16* __restrict__ A1,
    const __bf16* __restrict__ A2, const __bf16* __restrict__ Bw,
    void* __restrict__ C0, void* __restrict__ C1, void* __restrict__ C2) {
  constexpr int MI = TM / 32;
  __shared__ __bf16 As[TM][64];
  __shared__ __bf16 Bs[128][64];

  const int t    = threadIdx.x;
  const int lane = t & 63;
  const int wid  = t >> 6;
  const int wr   = (wid >> 1) * (TM / 2);
  const int wc   = (wid & 1) * 64;
  const int r16  = lane & 15;
  const int tm   = blockIdx.y * TM;
  const int tn   = blockIdx.x * 128;
  const int which = tn >> 10;

  const __bf16* Ab = (MODE == 0) ? (which == 0 ? A0 : which == 1 ? A1 : A2) : A0;

  f32x4 acc[MI][4] = {};

  for (int kt = 0; kt < E / 64; ++kt) {
    const int k0 = kt * 64;
    __syncthreads();
    constexpr int ACH = TM / 8;        // 1 KB chunks in A tile
    constexpr int NCH = ACH + 16;
#pragma unroll
    for (int c = wid; c < NCH; c += 4) {
      const bool isA = c < ACH;
      const int cc   = isA ? c : c - ACH;
      const int L    = cc * 1024 + lane * 16;   // byte offset in tile
      const int row  = L >> 7;                  // 128 B per row
      const int sw   = ((L >> 4) & 7) ^ (row & 7);
      const __bf16* src = isA ? &Ab[(size_t)(tm + row) * E + k0 + sw * 8]
                              : &Bw[(size_t)(tn + row) * E + k0 + sw * 8];
      char* dst = (isA ? (char*)As : (char*)Bs) + cc * 1024;
      GLOAD_LDS16(src, dst);
    }
    __syncthreads();
#pragma unroll
    for (int kc = 0; kc < 2; ++kc) {
      bf16x8 af[MI], bfv[4];
#pragma unroll
      for (int mi = 0; mi < MI; ++mi) {
        int row = wr + mi * 16 + r16;
        int g   = (kc * 4 + (lane >> 4)) ^ (row & 7);
        af[mi] = *reinterpret_cast<const bf16x8*>(&As[row][g * 8]);
      }
#pragma unroll
      for (int ni = 0; ni < 4; ++ni) {
        int row = wc + ni * 16 + r16;
        int g   = (kc * 4 + (lane >> 4)) ^ (row & 7);
        bfv[ni] = *reinterpret_cast<const bf16x8*>(&Bs[row][g * 8]);
      }
#pragma unroll
      for (int mi = 0; mi < MI; ++mi)
#pragma unroll
        for (int ni = 0; ni < 4; ++ni)
          acc[mi][ni] = __builtin_amdgcn_mfma_f32_16x16x32_bf16(af[mi], bfv[ni],
                                                                acc[mi][ni], 0, 0, 0);
    }
  }

#pragma unroll
  for (int mi = 0; mi < MI; ++mi) {
#pragma unroll
    for (int ni = 0; ni < 4; ++ni) {
#pragma unroll
      for (int j = 0; j < 4; ++j) {
        float v = acc[mi][ni][j];
        int m = tm + wr + mi * 16 + ((lane >> 4) << 2) + j;
        int n = tn + wc + ni * 16 + r16;
        if constexpr (MODE == 0) {
          int nl = n & 1023;
          int b = m >> 11, s = m & 2047, h = nl >> 6, d = nl & 63;
          __bf16* Cout = which == 0 ? (__bf16*)C0 : which == 1 ? (__bf16*)C1
                                                              : (__bf16*)C2;
          if (which < 2) {
            Cout[((size_t)(b * H + h) * S + s) * Dh + d] = (__bf16)v;
          } else {
            // PV chunk-order permutation: swap bits 2 and 3 of s
            int ssw = (s & ~12) | ((s & 4) << 1) | ((s & 8) >> 1);
            Cout[((size_t)(b * H + h) * Dh + d) * S + ssw] = (__bf16)v;
          }
        } else {
          ((float*)C0)[(size_t)m * E + n] = v;
        }
      }
    }
  }
}

// ---------------------------------------------------------------------------
// Sigmoid attention v3: 64 q-rows/block, 128 threads (2 waves x 32 q),
// double-buffered K/V (2-phase pipeline, 1 barrier/iter), zero cross-lane
// P exchange (V s-columns pre-permuted), sigmoid = rcp(1+exp2(y)) (scale
// folded into Wq), setprio around MFMA clusters, swizzled O-transpose.
// ---------------------------------------------------------------------------
__global__ __launch_bounds__(128) void attn_sigmoid(const __bf16* __restrict__ Q,
                                                    const __bf16* __restrict__ K,
                                                    const __bf16* __restrict__ Vt,
                                                    __bf16* __restrict__ O) {
  __shared__ char smem[2][16384];    // per buffer: K tile 8KB | V tile 8KB

  const int t    = threadIdx.x;
  const int lane = t & 63;
  const int wid  = t >> 6;           // 0..1
  const int l31  = lane & 31;
  const int hh   = lane >> 5;
  const int q0   = blockIdx.x * 64;
  const int h    = blockIdx.y;
  const int b    = blockIdx.z;

  const __bf16* Qh = Q + (size_t)(b * H + h) * S * Dh;
  const __bf16* Kh = K + (size_t)(b * H + h) * S * Dh;
  const __bf16* Vh = Vt + (size_t)(b * H + h) * Dh * S;

  // stage one KV tile (64 s x 64 d each) into buffer pb; XOR-swizzled source,
  // linear LDS dest. Per wave: 4 K-chunks + 4 V-chunks of 1KB.
  auto stage = [&](int st, int pb) {
    char* bK = &smem[pb][0];
    char* bV = &smem[pb][8192];
#pragma unroll
    for (int j = 0; j < 4; ++j) {
      int base = (wid * 4 + j) * 1024;
      int L    = base + lane * 16;
      int row  = L >> 7;
      int sw   = ((L >> 4) & 7) ^ (row & 7);
      GLOAD_LDS16(&Kh[(size_t)(st * 64 + row) * Dh + sw * 8], bK + base);
      GLOAD_LDS16(&Vh[(size_t)row * S + st * 64 + sw * 8], bV + base);
    }
  };

  stage(0, 0);

  // hoisted Q fragments (B-operand): Qf[kc] = Q[q0+wid*32+l31][kc*16+hh*8+..]
  bf16x8 Qf[4];
#pragma unroll
  for (int kc = 0; kc < 4; ++kc)
    Qf[kc] = *reinterpret_cast<const bf16x8*>(
        &Qh[(size_t)(q0 + wid * 32 + l31) * Dh + kc * 16 + hh * 8]);

  f32x16 ot0 = {}, ot1 = {};         // Ot[d][q], d blocks 0-31 / 32-63
  __syncthreads();                   // tile 0 ready

  for (int st = 0; st < S / 64; ++st) {
    const int cur = st & 1;
    if (st + 1 < S / 64) stage(st + 1, cur ^ 1);   // prefetch next tile

    const __bf16* Ks = (const __bf16*)&smem[cur][0];
    const __bf16* Vs = (const __bf16*)(&smem[cur][8192]);

    // ---- St = K Q^T (swapped): lane holds S[s][q=l31], two 32-s chains ----
    f32x16 s0 = {}, s1 = {};
    __builtin_amdgcn_s_setprio(1);
#pragma unroll
    for (int kc = 0; kc < 4; ++kc) {
      int x = (2 * kc + hh) ^ (l31 & 7);
      bf16x8 k0 = *reinterpret_cast<const bf16x8*>(&Ks[l31 * 64 + x * 8]);
      bf16x8 k1 = *reinterpret_cast<const bf16x8*>(&Ks[(32 + l31) * 64 + x * 8]);
      s0 = __builtin_amdgcn_mfma_f32_32x32x16_bf16(k0, Qf[kc], s0, 0, 0, 0);
      s1 = __builtin_amdgcn_mfma_f32_32x32x16_bf16(k1, Qf[kc], s1, 0, 0, 0);
    }
    __builtin_amdgcn_s_setprio(0);

    // ---- V fragments (issue LDS reads early, overlap with sigmoid) ----
    bf16x8 vf[8];
#pragma unroll
    for (int c = 0; c < 4; ++c) {
#pragma unroll
      for (int dblk = 0; dblk < 2; ++dblk) {
        int row = dblk * 32 + l31;
        int x   = (2 * c + hh) ^ (row & 7);
        vf[c * 2 + dblk] = *reinterpret_cast<const bf16x8*>(&Vs[row * 64 + x * 8]);
      }
    }

    // ---- sigmoid in-register: p = rcp(1 + 2^y); pack own 8 values/chunk ----
    bf16x8 F[4];
    {
      union { unsigned u[4]; bf16x8 v; } fu[4];
#pragma unroll
      for (int c = 0; c < 4; ++c) {
        int base = (c & 1) * 8;
#pragma unroll
        for (int jj = 0; jj < 4; ++jj) {
          float ya = (c < 2) ? s0[base + 2 * jj] : s1[base + 2 * jj];
          float yb = (c < 2) ? s0[base + 2 * jj + 1] : s1[base + 2 * jj + 1];
          float pa = __builtin_amdgcn_rcpf(1.0f + __builtin_amdgcn_exp2f(ya));
          float pb = __builtin_amdgcn_rcpf(1.0f + __builtin_amdgcn_exp2f(yb));
          fu[c].u[jj] = pk2(pa, pb);
        }
        F[c] = fu[c].v;
      }
    }

    // ---- Ot += Vt P (V columns pre-permuted -> F[c] is lane-local) ----
    __builtin_amdgcn_s_setprio(1);
#pragma unroll
    for (int c = 0; c < 4; ++c) {
      ot0 = __builtin_amdgcn_mfma_f32_32x32x16_bf16(vf[c * 2 + 0], F[c], ot0, 0, 0, 0);
      ot1 = __builtin_amdgcn_mfma_f32_32x32x16_bf16(vf[c * 2 + 1], F[c], ot1, 0, 0, 0);
    }
    __builtin_amdgcn_s_setprio(0);

    __syncthreads();   // drains vmcnt (next tile ready) + read-before-overwrite
  }

  // ---- epilogue: transpose Ot via swizzled Os[64][64], coalesced stores ----
  __bf16* Os = (__bf16*)&smem[0][0];
  {
    int row = wid * 32 + l31;          // q-row
#pragma unroll
    for (int dblk = 0; dblk < 2; ++dblk) {
#pragma unroll
      for (int rp = 0; rp < 4; ++rp) {
        int r  = rp * 4;
        int g  = dblk * 4 + rp;        // 16B granule index (d0>>3)
        int by = row * 128 + ((g ^ (row & 7)) * 16) + hh * 8;
        float a0 = dblk ? ot1[r]     : ot0[r];
        float a1 = dblk ? ot1[r + 1] : ot0[r + 1];
        float a2 = dblk ? ot1[r + 2] : ot0[r + 2];
        float a3 = dblk ? ot1[r + 3] : ot0[r + 3];
        unsigned long long val =
            (unsigned long long)pk2(a0, a1) | ((unsigned long long)pk2(a2, a3) << 32);
        *reinterpret_cast<unsigned long long*>((char*)Os + by) = val;
      }
    }
  }
  __syncthreads();
#pragma unroll
  for (int i = 0; i < 4; ++i) {
    int c   = i * 128 + t;
    int row = c >> 3;
    int ch  = c & 7;
    bf16x8 v = *reinterpret_cast<const bf16x8*>(
        (char*)Os + row * 128 + ((ch ^ (row & 7)) * 16));
    *reinterpret_cast<bf16x8*>(&O[((size_t)(b * S) + q0 + row) * E + h * Dh + ch * 8]) = v;
  }
}

extern "C" void kernel_launch(void* const* d_in, const int* in_sizes, int n_in,
                              void* d_out, int out_size, void* d_ws, size_t ws_size,
                              hipStream_t stream) {
  const float* query = (const float*)d_in[0];
  const float* key_  = (const float*)d_in[1];
  const float* value = (const float*)d_in[2];
  const float* Wq    = (const float*)d_in[3];
  const float* Wk    = (const float*)d_in[4];
  const float* Wv    = (const float*)d_in[5];
  const float* Wo    = (const float*)d_in[6];

  char* ws = (char*)d_ws;
  // layout (56 MB): act_q/k/v 24 MB | Wqkv 6 MB | Wob 2 MB | pq 8 | pk 8 | pvt 8
  __bf16* aq   = (__bf16*)(ws);                         // [M,E] bf16
  __bf16* ak   = (__bf16*)(ws + ((size_t)8 << 20));
  __bf16* av   = (__bf16*)(ws + ((size_t)16 << 20));
  __bf16* wqkv = (__bf16*)(ws + ((size_t)24 << 20));    // [3072,1024]
  __bf16* wob  = (__bf16*)(ws + ((size_t)30 << 20));    // [1024,1024]
  __bf16* pq   = (__bf16*)(ws + ((size_t)32 << 20));    // [B,H,S,D]
  __bf16* pk   = (__bf16*)(ws + ((size_t)40 << 20));    // [B,H,S,D]
  __bf16* pvt  = (__bf16*)(ws + ((size_t)48 << 20));    // [B,H,D,S] (s-perm)
  __bf16* ob   = (__bf16*)(ws);                         // [M,E] aliases dead act_q

  convert_bf16<<<dim3(512, 7), 256, 0, stream>>>(query, key_, value, Wq, Wk, Wv,
                                                 Wo, aq, ak, av, wqkv, wob);

  // merged QKV projection: C[4096,3072] over Wqkv, 768 blocks (3/CU)
  gemm_bf16nt<128, 0><<<dim3(3072 / 128, M / 128), 256, 0, stream>>>(
      aq, ak, av, wqkv, pq, pk, pvt);

  // attention: 64-q blocks, 128 threads -> 1024 blocks (4/CU)
  attn_sigmoid<<<dim3(S / 64, H, Bsz), 128, 0, stream>>>(pq, pk, pvt, ob);

  // final GEMM: 64-row tiles -> 512 blocks (2/CU)
  gemm_bf16nt<64, 2><<<dim3(E / 128, M / 64), 256, 0, stream>>>(
      ob, nullptr, nullptr, wob, (float*)d_out, nullptr, nullptr);
}

// Round 4
// 152.763 us; speedup vs baseline: 1.4923x; 1.0098x over previous
//
#include <hip/hip_runtime.h>

typedef float f32x4 __attribute__((ext_vector_type(4)));
typedef float f32x16 __attribute__((ext_vector_type(16)));
typedef __bf16 bf16x4 __attribute__((ext_vector_type(4)));
typedef __bf16 bf16x8 __attribute__((ext_vector_type(8)));

constexpr int E = 1024;   // embed dim = K for all GEMMs
constexpr int S = 2048;   // sequence length
constexpr int Bsz = 2;    // batch
constexpr int H = 16;     // heads
constexpr int Dh = 64;    // head dim
constexpr int M = Bsz * S; // 4096 rows for projection GEMMs

#define GLOAD_LDS16(g, l)                                                                 \
  __builtin_amdgcn_global_load_lds((const __attribute__((address_space(1))) void*)(g),    \
                                   (__attribute__((address_space(3))) void*)(l), 16, 0, 0)

__device__ __forceinline__ unsigned pk2(float a, float b) {
  union { __bf16 h[2]; unsigned u; } r;
  r.h[0] = (__bf16)a; r.h[1] = (__bf16)b;
  return r.u;
}

// ---------------------------------------------------------------------------
// fp32 -> bf16 convert pass. blockIdx.y picks tensor:
// 0..2: query/key/value [M,E];  3..5: Wq*(-0.125*log2e) / Wk / Wv -> Wqkv;
// 6: Wo -> Wob.  (Q scale folded so sigmoid = rcp(1 + exp2(qk)).)
// ---------------------------------------------------------------------------
__global__ __launch_bounds__(256) void convert_bf16(
    const float* __restrict__ q, const float* __restrict__ k,
    const float* __restrict__ v, const float* __restrict__ wq,
    const float* __restrict__ wk, const float* __restrict__ wv,
    const float* __restrict__ wo, __bf16* __restrict__ aq,
    __bf16* __restrict__ ak, __bf16* __restrict__ av,
    __bf16* __restrict__ wqkv, __bf16* __restrict__ wob) {
  const int id = blockIdx.y;
  const float* src;
  __bf16* dst;
  int n;
  float scale = 1.0f;
  switch (id) {
    case 0: src = q;  dst = aq;             n = M * E; break;
    case 1: src = k;  dst = ak;             n = M * E; break;
    case 2: src = v;  dst = av;             n = M * E; break;
    case 3: src = wq; dst = wqkv;           n = E * E; scale = -0.18033688f; break;
    case 4: src = wk; dst = wqkv + E * E;   n = E * E; break;
    case 5: src = wv; dst = wqkv + 2 * E * E; n = E * E; break;
    default: src = wo; dst = wob;           n = E * E; break;
  }
  const int stride = gridDim.x * 256 * 8;
  for (int i = (blockIdx.x * 256 + threadIdx.x) * 8; i < n; i += stride) {
    f32x4 a = *reinterpret_cast<const f32x4*>(&src[i]);
    f32x4 b = *reinterpret_cast<const f32x4*>(&src[i + 4]);
    bf16x8 o;
    o[0] = (__bf16)(a[0] * scale); o[1] = (__bf16)(a[1] * scale);
    o[2] = (__bf16)(a[2] * scale); o[3] = (__bf16)(a[3] * scale);
    o[4] = (__bf16)(b[0] * scale); o[5] = (__bf16)(b[1] * scale);
    o[6] = (__bf16)(b[2] * scale); o[7] = (__bf16)(b[3] * scale);
    *reinterpret_cast<bf16x8*>(&dst[i]) = o;
  }
}

// ---------------------------------------------------------------------------
// bf16 NT GEMM, m97 structure (unchanged from round 3).
// ---------------------------------------------------------------------------
template <int TM, int MODE>
__global__ __launch_bounds__(256) void gemm_bf16nt(
    const __bf16* __restrict__ A0, const __bf16* __restrict__ A1,
    const __bf16* __restrict__ A2, const __bf16* __restrict__ Bw,
    void* __restrict__ C0, void* __restrict__ C1, void* __restrict__ C2) {
  constexpr int MI = TM / 32;
  __shared__ __bf16 As[TM][64];
  __shared__ __bf16 Bs[128][64];

  const int t    = threadIdx.x;
  const int lane = t & 63;
  const int wid  = t >> 6;
  const int wr   = (wid >> 1) * (TM / 2);
  const int wc   = (wid & 1) * 64;
  const int r16  = lane & 15;
  const int tm   = blockIdx.y * TM;
  const int tn   = blockIdx.x * 128;
  const int which = tn >> 10;

  const __bf16* Ab = (MODE == 0) ? (which == 0 ? A0 : which == 1 ? A1 : A2) : A0;

  f32x4 acc[MI][4] = {};

  for (int kt = 0; kt < E / 64; ++kt) {
    const int k0 = kt * 64;
    __syncthreads();
    constexpr int ACH = TM / 8;        // 1 KB chunks in A tile
    constexpr int NCH = ACH + 16;
#pragma unroll
    for (int c = wid; c < NCH; c += 4) {
      const bool isA = c < ACH;
      const int cc   = isA ? c : c - ACH;
      const int L    = cc * 1024 + lane * 16;   // byte offset in tile
      const int row  = L >> 7;                  // 128 B per row
      const int sw   = ((L >> 4) & 7) ^ (row & 7);
      const __bf16* src = isA ? &Ab[(size_t)(tm + row) * E + k0 + sw * 8]
                              : &Bw[(size_t)(tn + row) * E + k0 + sw * 8];
      char* dst = (isA ? (char*)As : (char*)Bs) + cc * 1024;
      GLOAD_LDS16(src, dst);
    }
    __syncthreads();
#pragma unroll
    for (int kc = 0; kc < 2; ++kc) {
      bf16x8 af[MI], bfv[4];
#pragma unroll
      for (int mi = 0; mi < MI; ++mi) {
        int row = wr + mi * 16 + r16;
        int g   = (kc * 4 + (lane >> 4)) ^ (row & 7);
        af[mi] = *reinterpret_cast<const bf16x8*>(&As[row][g * 8]);
      }
#pragma unroll
      for (int ni = 0; ni < 4; ++ni) {
        int row = wc + ni * 16 + r16;
        int g   = (kc * 4 + (lane >> 4)) ^ (row & 7);
        bfv[ni] = *reinterpret_cast<const bf16x8*>(&Bs[row][g * 8]);
      }
#pragma unroll
      for (int mi = 0; mi < MI; ++mi)
#pragma unroll
        for (int ni = 0; ni < 4; ++ni)
          acc[mi][ni] = __builtin_amdgcn_mfma_f32_16x16x32_bf16(af[mi], bfv[ni],
                                                                acc[mi][ni], 0, 0, 0);
    }
  }

#pragma unroll
  for (int mi = 0; mi < MI; ++mi) {
#pragma unroll
    for (int ni = 0; ni < 4; ++ni) {
#pragma unroll
      for (int j = 0; j < 4; ++j) {
        float v = acc[mi][ni][j];
        int m = tm + wr + mi * 16 + ((lane >> 4) << 2) + j;
        int n = tn + wc + ni * 16 + r16;
        if constexpr (MODE == 0) {
          int nl = n & 1023;
          int b = m >> 11, s = m & 2047, h = nl >> 6, d = nl & 63;
          __bf16* Cout = which == 0 ? (__bf16*)C0 : which == 1 ? (__bf16*)C1
                                                              : (__bf16*)C2;
          if (which < 2) {
            Cout[((size_t)(b * H + h) * S + s) * Dh + d] = (__bf16)v;
          } else {
            // PV chunk-order permutation: swap bits 2 and 3 of s
            int ssw = (s & ~12) | ((s & 4) << 1) | ((s & 8) >> 1);
            Cout[((size_t)(b * H + h) * Dh + d) * S + ssw] = (__bf16)v;
          }
        } else {
          ((float*)C0)[(size_t)m * E + n] = v;
        }
      }
    }
  }
}

// ---------------------------------------------------------------------------
// Sigmoid attention v4: 256 threads = 4 waves; wave w = (qgrp=w&1, shalf=w>>1).
// s-dimension split across wave pairs (16 waves/CU = 4/SIMD), KVBLK=32 per
// half, double-buffered (LDS 32KB). f32 partial-sum combine via LDS epilogue.
// Zero cross-lane P exchange (V s-cols pre-permuted); sigmoid=rcp(1+exp2(y)).
// ---------------------------------------------------------------------------
__global__ __launch_bounds__(256) void attn_sigmoid(const __bf16* __restrict__ Q,
                                                    const __bf16* __restrict__ K,
                                                    const __bf16* __restrict__ Vt,
                                                    __bf16* __restrict__ O) {
  // [shalf][buf]: K tile 4KB (32s x 64d) + V tile 4KB (64d x 32s) = 8KB
  __shared__ char smem[32768];

  const int t     = threadIdx.x;
  const int lane  = t & 63;
  const int wid   = t >> 6;
  const int l31   = lane & 31;
  const int hh    = lane >> 5;
  const int qgrp  = wid & 1;
  const int shalf = wid >> 1;
  const int q0    = blockIdx.x * 64;
  const int h     = blockIdx.y;
  const int b     = blockIdx.z;

  const __bf16* Qh = Q + (size_t)(b * H + h) * S * Dh;
  const __bf16* Kh = K + (size_t)(b * H + h) * S * Dh;
  const __bf16* Vh = Vt + (size_t)(b * H + h) * Dh * S;

  char* const myBase = smem + shalf * 16384;

  // per-lane swizzled source pointers (computed once; per-iter = const adds)
  // K stager (qgrp==0): lane -> row (lane>>3), granule (lane&7)^(lane>>3)
  const __bf16* kSrc = Kh + (size_t)(shalf * 1024 + (lane >> 3)) * Dh +
                       (((lane & 7) ^ (lane >> 3)) * 8);
  // V stager (qgrp==1): lane -> d-row (lane>>2), s-granule (lane&3)^((lane>>3)&3)
  const __bf16* vSrc = Vh + (size_t)(lane >> 2) * S + shalf * 1024 +
                       (((lane & 3) ^ ((lane >> 3) & 3)) * 8);

  auto stage = [&](int it, int buf) {
    char* dst = myBase + buf * 8192;
    if (qgrp == 0) {
#pragma unroll
      for (int j = 0; j < 4; ++j)
        GLOAD_LDS16(kSrc + it * 2048 + j * 512, dst + j * 1024);
    } else {
#pragma unroll
      for (int j = 0; j < 4; ++j)
        GLOAD_LDS16(vSrc + it * 32 + (size_t)j * 16 * S, dst + 4096 + j * 1024);
    }
  };

  stage(0, 0);

  // hoisted Q fragments: Qf[kc] = Q[q0+qgrp*32+l31][kc*16 + hh*8 + 0..7]
  bf16x8 Qf[4];
#pragma unroll
  for (int kc = 0; kc < 4; ++kc)
    Qf[kc] = *reinterpret_cast<const bf16x8*>(
        &Qh[(size_t)(q0 + qgrp * 32 + l31) * Dh + kc * 16 + hh * 8]);

  f32x16 ot0 = {}, ot1 = {};   // Ot[d][q]: d 0-31 / 32-63, q = this wave's 32
  __syncthreads();             // tile 0 staged

#pragma unroll 2
  for (int it = 0; it < 32; ++it) {
    const int buf = it & 1;
    if (it + 1 < 32) stage(it + 1, buf ^ 1);

    const __bf16* Kb = (const __bf16*)(myBase + buf * 8192);
    const __bf16* Vb = (const __bf16*)(myBase + buf * 8192 + 4096);

    // fragment reads (issued together; sigmoid overlaps V arrival)
    bf16x8 kf[4], vf[4];
#pragma unroll
    for (int kc = 0; kc < 4; ++kc) {
      int x = (2 * kc + hh) ^ (l31 & 7);
      kf[kc] = *reinterpret_cast<const bf16x8*>(&Kb[l31 * 64 + x * 8]);
    }
#pragma unroll
    for (int kc2 = 0; kc2 < 2; ++kc2)
#pragma unroll
      for (int dblk = 0; dblk < 2; ++dblk) {
        int row = dblk * 32 + l31;
        int x   = (2 * kc2 + hh) ^ ((l31 >> 1) & 3);
        vf[kc2 * 2 + dblk] = *reinterpret_cast<const bf16x8*>(&Vb[row * 32 + x * 8]);
      }

    // ---- St = K Q^T (swapped): lane holds S[s][q=l31], s = 32-tile ----
    f32x16 sacc = {};
    __builtin_amdgcn_s_setprio(1);
#pragma unroll
    for (int kc = 0; kc < 4; ++kc)
      sacc = __builtin_amdgcn_mfma_f32_32x32x16_bf16(kf[kc], Qf[kc], sacc, 0, 0, 0);
    __builtin_amdgcn_s_setprio(0);

    // ---- sigmoid in-register; F[kc2] = packed p[kc2*8 .. +7] ----
    bf16x8 F[2];
    {
      union { unsigned u[4]; bf16x8 v; } fu[2];
#pragma unroll
      for (int kc2 = 0; kc2 < 2; ++kc2) {
#pragma unroll
        for (int jj = 0; jj < 4; ++jj) {
          float ya = sacc[kc2 * 8 + 2 * jj];
          float yb = sacc[kc2 * 8 + 2 * jj + 1];
          float pa = __builtin_amdgcn_rcpf(1.0f + __builtin_amdgcn_exp2f(ya));
          float pb = __builtin_amdgcn_rcpf(1.0f + __builtin_amdgcn_exp2f(yb));
          fu[kc2].u[jj] = pk2(pa, pb);
        }
        F[kc2] = fu[kc2].v;
      }
    }

    // ---- Ot += Vt P (V s-cols pre-permuted -> F lane-local) ----
    __builtin_amdgcn_s_setprio(1);
    ot0 = __builtin_amdgcn_mfma_f32_32x32x16_bf16(vf[0], F[0], ot0, 0, 0, 0);
    ot1 = __builtin_amdgcn_mfma_f32_32x32x16_bf16(vf[1], F[0], ot1, 0, 0, 0);
    ot0 = __builtin_amdgcn_mfma_f32_32x32x16_bf16(vf[2], F[1], ot0, 0, 0, 0);
    ot1 = __builtin_amdgcn_mfma_f32_32x32x16_bf16(vf[3], F[1], ot1, 0, 0, 0);
    __builtin_amdgcn_s_setprio(0);

    __syncthreads();   // drains vmcnt (next tile staged) + LDS reads done
  }

  // ---- epilogue: f32 partial combine (shalf1 -> LDS -> shalf0 adds) ----
  const int q = qgrp * 32 + l31;
  {
    char* Ps = smem;   // [64 q][256 B] f32, XOR-swizzled 16B granules
    if (shalf == 1) {
#pragma unroll
      for (int dblk = 0; dblk < 2; ++dblk)
#pragma unroll
        for (int rp = 0; rp < 4; ++rp) {
          int gg = dblk * 8 + rp * 2 + hh;
          int r  = rp * 4;
          f32x4 v;
          v[0] = dblk ? ot1[r]     : ot0[r];
          v[1] = dblk ? ot1[r + 1] : ot0[r + 1];
          v[2] = dblk ? ot1[r + 2] : ot0[r + 2];
          v[3] = dblk ? ot1[r + 3] : ot0[r + 3];
          *reinterpret_cast<f32x4*>(Ps + q * 256 + ((gg ^ (q & 7)) * 16)) = v;
        }
    }
    __syncthreads();
    if (shalf == 0) {
#pragma unroll
      for (int dblk = 0; dblk < 2; ++dblk)
#pragma unroll
        for (int rp = 0; rp < 4; ++rp) {
          int gg = dblk * 8 + rp * 2 + hh;
          int r  = rp * 4;
          f32x4 v = *reinterpret_cast<const f32x4*>(Ps + q * 256 + ((gg ^ (q & 7)) * 16));
          if (dblk) {
            ot1[r] += v[0]; ot1[r + 1] += v[1]; ot1[r + 2] += v[2]; ot1[r + 3] += v[3];
          } else {
            ot0[r] += v[0]; ot0[r + 1] += v[1]; ot0[r + 2] += v[2]; ot0[r + 3] += v[3];
          }
        }
    }
  }
  __syncthreads();

  // ---- transpose summed Ot via swizzled Os[64][64], coalesced stores ----
  __bf16* Os = (__bf16*)smem;
  if (shalf == 0) {
    int row = q;
#pragma unroll
    for (int dblk = 0; dblk < 2; ++dblk)
#pragma unroll
      for (int rp = 0; rp < 4; ++rp) {
        int r  = rp * 4;
        int g  = dblk * 4 + rp;
        int by = row * 128 + ((g ^ (row & 7)) * 16) + hh * 8;
        float a0 = dblk ? ot1[r]     : ot0[r];
        float a1 = dblk ? ot1[r + 1] : ot0[r + 1];
        float a2 = dblk ? ot1[r + 2] : ot0[r + 2];
        float a3 = dblk ? ot1[r + 3] : ot0[r + 3];
        unsigned long long val =
            (unsigned long long)pk2(a0, a1) | ((unsigned long long)pk2(a2, a3) << 32);
        *reinterpret_cast<unsigned long long*>((char*)Os + by) = val;
      }
  }
  __syncthreads();
#pragma unroll
  for (int i = 0; i < 2; ++i) {
    int c   = i * 256 + t;
    int row = c >> 3;
    int ch  = c & 7;
    bf16x8 v = *reinterpret_cast<const bf16x8*>(
        (char*)Os + row * 128 + ((ch ^ (row & 7)) * 16));
    *reinterpret_cast<bf16x8*>(&O[((size_t)(b * S) + q0 + row) * E + h * Dh + ch * 8]) = v;
  }
}

extern "C" void kernel_launch(void* const* d_in, const int* in_sizes, int n_in,
                              void* d_out, int out_size, void* d_ws, size_t ws_size,
                              hipStream_t stream) {
  const float* query = (const float*)d_in[0];
  const float* key_  = (const float*)d_in[1];
  const float* value = (const float*)d_in[2];
  const float* Wq    = (const float*)d_in[3];
  const float* Wk    = (const float*)d_in[4];
  const float* Wv    = (const float*)d_in[5];
  const float* Wo    = (const float*)d_in[6];

  char* ws = (char*)d_ws;
  // layout (56 MB): act_q/k/v 24 MB | Wqkv 6 MB | Wob 2 MB | pq 8 | pk 8 | pvt 8
  __bf16* aq   = (__bf16*)(ws);                         // [M,E] bf16
  __bf16* ak   = (__bf16*)(ws + ((size_t)8 << 20));
  __bf16* av   = (__bf16*)(ws + ((size_t)16 << 20));
  __bf16* wqkv = (__bf16*)(ws + ((size_t)24 << 20));    // [3072,1024]
  __bf16* wob  = (__bf16*)(ws + ((size_t)30 << 20));    // [1024,1024]
  __bf16* pq   = (__bf16*)(ws + ((size_t)32 << 20));    // [B,H,S,D]
  __bf16* pk   = (__bf16*)(ws + ((size_t)40 << 20));    // [B,H,S,D]
  __bf16* pvt  = (__bf16*)(ws + ((size_t)48 << 20));    // [B,H,D,S] (s-perm)
  __bf16* ob   = (__bf16*)(ws);                         // [M,E] aliases dead act_q

  convert_bf16<<<dim3(512, 7), 256, 0, stream>>>(query, key_, value, Wq, Wk, Wv,
                                                 Wo, aq, ak, av, wqkv, wob);

  // merged QKV projection: C[4096,3072] over Wqkv, 768 blocks (3/CU)
  gemm_bf16nt<128, 0><<<dim3(3072 / 128, M / 128), 256, 0, stream>>>(
      aq, ak, av, wqkv, pq, pk, pvt);

  // attention: 64-q blocks, 256 threads (4 waves, s-split in block) -> 1024 blocks
  attn_sigmoid<<<dim3(S / 64, H, Bsz), 256, 0, stream>>>(pq, pk, pvt, ob);

  // final GEMM: 64-row tiles -> 512 blocks (2/CU)
  gemm_bf16nt<64, 2><<<dim3(E / 128, M / 64), 256, 0, stream>>>(
      ob, nullptr, nullptr, wob, (float*)d_out, nullptr, nullptr);
}

// Round 5
// 152.335 us; speedup vs baseline: 1.4965x; 1.0028x over previous
//
#include <hip/hip_runtime.h>

typedef float f32x4 __attribute__((ext_vector_type(4)));
typedef float f32x16 __attribute__((ext_vector_type(16)));
typedef __bf16 bf16x4 __attribute__((ext_vector_type(4)));
typedef __bf16 bf16x8 __attribute__((ext_vector_type(8)));

constexpr int E = 1024;   // embed dim = K for all GEMMs
constexpr int S = 2048;   // sequence length
constexpr int Bsz = 2;    // batch
constexpr int H = 16;     // heads
constexpr int Dh = 64;    // head dim
constexpr int M = Bsz * S; // 4096 rows for projection GEMMs

#define GLOAD_LDS16(g, l)                                                                 \
  __builtin_amdgcn_global_load_lds((const __attribute__((address_space(1))) void*)(g),    \
                                   (__attribute__((address_space(3))) void*)(l), 16, 0, 0)

__device__ __forceinline__ unsigned pk2(float a, float b) {
  union { __bf16 h[2]; unsigned u; } r;
  r.h[0] = (__bf16)a; r.h[1] = (__bf16)b;
  return r.u;
}

// ---------------------------------------------------------------------------
// fp32 -> bf16 convert pass. blockIdx.y picks tensor:
// 0..2: query/key/value [M,E];  3..5: Wq*(-0.125*log2e) / Wk / Wv -> Wqkv;
// 6: Wo -> Wob.  (Q scale folded so sigmoid = rcp(1 + exp2(qk)).)
// ---------------------------------------------------------------------------
__global__ __launch_bounds__(256) void convert_bf16(
    const float* __restrict__ q, const float* __restrict__ k,
    const float* __restrict__ v, const float* __restrict__ wq,
    const float* __restrict__ wk, const float* __restrict__ wv,
    const float* __restrict__ wo, __bf16* __restrict__ aq,
    __bf16* __restrict__ ak, __bf16* __restrict__ av,
    __bf16* __restrict__ wqkv, __bf16* __restrict__ wob) {
  const int id = blockIdx.y;
  const float* src;
  __bf16* dst;
  int n;
  float scale = 1.0f;
  switch (id) {
    case 0: src = q;  dst = aq;             n = M * E; break;
    case 1: src = k;  dst = ak;             n = M * E; break;
    case 2: src = v;  dst = av;             n = M * E; break;
    case 3: src = wq; dst = wqkv;           n = E * E; scale = -0.18033688f; break;
    case 4: src = wk; dst = wqkv + E * E;   n = E * E; break;
    case 5: src = wv; dst = wqkv + 2 * E * E; n = E * E; break;
    default: src = wo; dst = wob;           n = E * E; break;
  }
  const int stride = gridDim.x * 256 * 8;
  for (int i = (blockIdx.x * 256 + threadIdx.x) * 8; i < n; i += stride) {
    f32x4 a = *reinterpret_cast<const f32x4*>(&src[i]);
    f32x4 b = *reinterpret_cast<const f32x4*>(&src[i + 4]);
    bf16x8 o;
    o[0] = (__bf16)(a[0] * scale); o[1] = (__bf16)(a[1] * scale);
    o[2] = (__bf16)(a[2] * scale); o[3] = (__bf16)(a[3] * scale);
    o[4] = (__bf16)(b[0] * scale); o[5] = (__bf16)(b[1] * scale);
    o[6] = (__bf16)(b[2] * scale); o[7] = (__bf16)(b[3] * scale);
    *reinterpret_cast<bf16x8*>(&dst[i]) = o;
  }
}

// ---------------------------------------------------------------------------
// bf16 NT GEMM, m97 structure (unchanged, verified).
// ---------------------------------------------------------------------------
template <int TM, int MODE>
__global__ __launch_bounds__(256) void gemm_bf16nt(
    const __bf16* __restrict__ A0, const __bf16* __restrict__ A1,
    const __bf16* __restrict__ A2, const __bf16* __restrict__ Bw,
    void* __restrict__ C0, void* __restrict__ C1, void* __restrict__ C2) {
  constexpr int MI = TM / 32;
  __shared__ __bf16 As[TM][64];
  __shared__ __bf16 Bs[128][64];

  const int t    = threadIdx.x;
  const int lane = t & 63;
  const int wid  = t >> 6;
  const int wr   = (wid >> 1) * (TM / 2);
  const int wc   = (wid & 1) * 64;
  const int r16  = lane & 15;
  const int tm   = blockIdx.y * TM;
  const int tn   = blockIdx.x * 128;
  const int which = tn >> 10;

  const __bf16* Ab = (MODE == 0) ? (which == 0 ? A0 : which == 1 ? A1 : A2) : A0;

  f32x4 acc[MI][4] = {};

  for (int kt = 0; kt < E / 64; ++kt) {
    const int k0 = kt * 64;
    __syncthreads();
    constexpr int ACH = TM / 8;        // 1 KB chunks in A tile
    constexpr int NCH = ACH + 16;
#pragma unroll
    for (int c = wid; c < NCH; c += 4) {
      const bool isA = c < ACH;
      const int cc   = isA ? c : c - ACH;
      const int L    = cc * 1024 + lane * 16;   // byte offset in tile
      const int row  = L >> 7;                  // 128 B per row
      const int sw   = ((L >> 4) & 7) ^ (row & 7);
      const __bf16* src = isA ? &Ab[(size_t)(tm + row) * E + k0 + sw * 8]
                              : &Bw[(size_t)(tn + row) * E + k0 + sw * 8];
      char* dst = (isA ? (char*)As : (char*)Bs) + cc * 1024;
      GLOAD_LDS16(src, dst);
    }
    __syncthreads();
#pragma unroll
    for (int kc = 0; kc < 2; ++kc) {
      bf16x8 af[MI], bfv[4];
#pragma unroll
      for (int mi = 0; mi < MI; ++mi) {
        int row = wr + mi * 16 + r16;
        int g   = (kc * 4 + (lane >> 4)) ^ (row & 7);
        af[mi] = *reinterpret_cast<const bf16x8*>(&As[row][g * 8]);
      }
#pragma unroll
      for (int ni = 0; ni < 4; ++ni) {
        int row = wc + ni * 16 + r16;
        int g   = (kc * 4 + (lane >> 4)) ^ (row & 7);
        bfv[ni] = *reinterpret_cast<const bf16x8*>(&Bs[row][g * 8]);
      }
#pragma unroll
      for (int mi = 0; mi < MI; ++mi)
#pragma unroll
        for (int ni = 0; ni < 4; ++ni)
          acc[mi][ni] = __builtin_amdgcn_mfma_f32_16x16x32_bf16(af[mi], bfv[ni],
                                                                acc[mi][ni], 0, 0, 0);
    }
  }

#pragma unroll
  for (int mi = 0; mi < MI; ++mi) {
#pragma unroll
    for (int ni = 0; ni < 4; ++ni) {
#pragma unroll
      for (int j = 0; j < 4; ++j) {
        float v = acc[mi][ni][j];
        int m = tm + wr + mi * 16 + ((lane >> 4) << 2) + j;
        int n = tn + wc + ni * 16 + r16;
        if constexpr (MODE == 0) {
          int nl = n & 1023;
          int b = m >> 11, s = m & 2047, h = nl >> 6, d = nl & 63;
          __bf16* Cout = which == 0 ? (__bf16*)C0 : which == 1 ? (__bf16*)C1
                                                              : (__bf16*)C2;
          if (which < 2) {
            Cout[((size_t)(b * H + h) * S + s) * Dh + d] = (__bf16)v;
          } else {
            // PV chunk-order permutation: swap bits 2 and 3 of s
            int ssw = (s & ~12) | ((s & 4) << 1) | ((s & 8) >> 1);
            Cout[((size_t)(b * H + h) * Dh + d) * S + ssw] = (__bf16)v;
          }
        } else {
          ((float*)C0)[(size_t)m * E + n] = v;
        }
      }
    }
  }
}

// ---------------------------------------------------------------------------
// Sigmoid attention v5: v4 structure (4 waves: qgrp=w&1, shalf=w>>1; KVBLK=32
// per half, dbuf) but counted-vmcnt pipeline: NO vmcnt(0) drain in main loop.
// Per iter: vmcnt(4) [tile t landed, t+1 in flight] -> s_barrier -> compute(t)
// -> s_barrier -> stage(t+2) into freed buffer. Depth-2 prefetch.
// ---------------------------------------------------------------------------
__global__ __launch_bounds__(256) void attn_sigmoid(const __bf16* __restrict__ Q,
                                                    const __bf16* __restrict__ K,
                                                    const __bf16* __restrict__ Vt,
                                                    __bf16* __restrict__ O) {
  // [shalf][buf]: K tile 4KB (32s x 64d) + V tile 4KB (64d x 32s) = 8KB
  __shared__ char smem[32768];

  const int t     = threadIdx.x;
  const int lane  = t & 63;
  const int wid   = t >> 6;
  const int l31   = lane & 31;
  const int hh    = lane >> 5;
  const int qgrp  = wid & 1;
  const int shalf = wid >> 1;
  const int q0    = blockIdx.x * 64;
  const int h     = blockIdx.y;
  const int b     = blockIdx.z;

  const __bf16* Qh = Q + (size_t)(b * H + h) * S * Dh;
  const __bf16* Kh = K + (size_t)(b * H + h) * S * Dh;
  const __bf16* Vh = Vt + (size_t)(b * H + h) * Dh * S;

  char* const myBase = smem + shalf * 16384;

  // per-lane swizzled source pointers (computed once)
  const __bf16* kSrc = Kh + (size_t)(shalf * 1024 + (lane >> 3)) * Dh +
                       (((lane & 7) ^ (lane >> 3)) * 8);
  const __bf16* vSrc = Vh + (size_t)(lane >> 2) * S + shalf * 1024 +
                       (((lane & 3) ^ ((lane >> 3) & 3)) * 8);

  auto stage = [&](int it, int buf) {
    char* dst = myBase + buf * 8192;
    if (qgrp == 0) {
#pragma unroll
      for (int j = 0; j < 4; ++j)
        GLOAD_LDS16(kSrc + it * 2048 + j * 512, dst + j * 1024);
    } else {
#pragma unroll
      for (int j = 0; j < 4; ++j)
        GLOAD_LDS16(vSrc + it * 32 + (size_t)j * 16 * S, dst + 4096 + j * 1024);
    }
  };

  // hoisted Q fragments (issued first; FIFO-retired before tile waits)
  bf16x8 Qf[4];
#pragma unroll
  for (int kc = 0; kc < 4; ++kc)
    Qf[kc] = *reinterpret_cast<const bf16x8*>(
        &Qh[(size_t)(q0 + qgrp * 32 + l31) * Dh + kc * 16 + hh * 8]);

  // depth-2 prefetch: tiles 0 and 1 in flight
  stage(0, 0);
  stage(1, 1);

  f32x16 ot0 = {}, ot1 = {};   // Ot[d][q]: d 0-31 / 32-63, q = this wave's 32

#pragma unroll 2
  for (int it = 0; it < 32; ++it) {
    const int buf = it & 1;
    // wait for tile it's 4 staging loads (oldest in FIFO); keep t+1's in flight
    if (it + 1 < 32) {
      asm volatile("s_waitcnt vmcnt(4)" ::: "memory");
    } else {
      asm volatile("s_waitcnt vmcnt(0)" ::: "memory");
    }
    __builtin_amdgcn_s_barrier();          // all waves' tile-it writes visible
    __builtin_amdgcn_sched_barrier(0);

    const __bf16* Kb = (const __bf16*)(myBase + buf * 8192);
    const __bf16* Vb = (const __bf16*)(myBase + buf * 8192 + 4096);

    // fragment reads
    bf16x8 kf[4], vf[4];
#pragma unroll
    for (int kc = 0; kc < 4; ++kc) {
      int x = (2 * kc + hh) ^ (l31 & 7);
      kf[kc] = *reinterpret_cast<const bf16x8*>(&Kb[l31 * 64 + x * 8]);
    }
#pragma unroll
    for (int kc2 = 0; kc2 < 2; ++kc2)
#pragma unroll
      for (int dblk = 0; dblk < 2; ++dblk) {
        int row = dblk * 32 + l31;
        int x   = (2 * kc2 + hh) ^ ((l31 >> 1) & 3);
        vf[kc2 * 2 + dblk] = *reinterpret_cast<const bf16x8*>(&Vb[row * 32 + x * 8]);
      }

    // ---- St = K Q^T (swapped): lane holds S[s][q=l31] ----
    f32x16 sacc = {};
    __builtin_amdgcn_s_setprio(1);
#pragma unroll
    for (int kc = 0; kc < 4; ++kc)
      sacc = __builtin_amdgcn_mfma_f32_32x32x16_bf16(kf[kc], Qf[kc], sacc, 0, 0, 0);
    __builtin_amdgcn_s_setprio(0);

    // ---- sigmoid in-register; F[kc2] = packed p[kc2*8 .. +7] ----
    bf16x8 F[2];
    {
      union { unsigned u[4]; bf16x8 v; } fu[2];
#pragma unroll
      for (int kc2 = 0; kc2 < 2; ++kc2) {
#pragma unroll
        for (int jj = 0; jj < 4; ++jj) {
          float ya = sacc[kc2 * 8 + 2 * jj];
          float yb = sacc[kc2 * 8 + 2 * jj + 1];
          float pa = __builtin_amdgcn_rcpf(1.0f + __builtin_amdgcn_exp2f(ya));
          float pb = __builtin_amdgcn_rcpf(1.0f + __builtin_amdgcn_exp2f(yb));
          fu[kc2].u[jj] = pk2(pa, pb);
        }
        F[kc2] = fu[kc2].v;
      }
    }

    // ---- Ot += Vt P (V s-cols pre-permuted -> F lane-local) ----
    __builtin_amdgcn_s_setprio(1);
    ot0 = __builtin_amdgcn_mfma_f32_32x32x16_bf16(vf[0], F[0], ot0, 0, 0, 0);
    ot1 = __builtin_amdgcn_mfma_f32_32x32x16_bf16(vf[1], F[0], ot1, 0, 0, 0);
    ot0 = __builtin_amdgcn_mfma_f32_32x32x16_bf16(vf[2], F[1], ot0, 0, 0, 0);
    ot1 = __builtin_amdgcn_mfma_f32_32x32x16_bf16(vf[3], F[1], ot1, 0, 0, 0);
    __builtin_amdgcn_s_setprio(0);

    __builtin_amdgcn_sched_barrier(0);
    __builtin_amdgcn_s_barrier();          // all readers of buf done
    if (it + 2 < 32) stage(it + 2, buf);   // refill freed buffer (no drain)
  }

  __syncthreads();   // full drain before LDS reuse in epilogue

  // ---- epilogue: f32 partial combine (shalf1 -> LDS -> shalf0 adds) ----
  const int q = qgrp * 32 + l31;
  {
    char* Ps = smem;   // [64 q][256 B] f32, XOR-swizzled 16B granules
    if (shalf == 1) {
#pragma unroll
      for (int dblk = 0; dblk < 2; ++dblk)
#pragma unroll
        for (int rp = 0; rp < 4; ++rp) {
          int gg = dblk * 8 + rp * 2 + hh;
          int r  = rp * 4;
          f32x4 v;
          v[0] = dblk ? ot1[r]     : ot0[r];
          v[1] = dblk ? ot1[r + 1] : ot0[r + 1];
          v[2] = dblk ? ot1[r + 2] : ot0[r + 2];
          v[3] = dblk ? ot1[r + 3] : ot0[r + 3];
          *reinterpret_cast<f32x4*>(Ps + q * 256 + ((gg ^ (q & 7)) * 16)) = v;
        }
    }
    __syncthreads();
    if (shalf == 0) {
#pragma unroll
      for (int dblk = 0; dblk < 2; ++dblk)
#pragma unroll
        for (int rp = 0; rp < 4; ++rp) {
          int gg = dblk * 8 + rp * 2 + hh;
          int r  = rp * 4;
          f32x4 v = *reinterpret_cast<const f32x4*>(Ps + q * 256 + ((gg ^ (q & 7)) * 16));
          if (dblk) {
            ot1[r] += v[0]; ot1[r + 1] += v[1]; ot1[r + 2] += v[2]; ot1[r + 3] += v[3];
          } else {
            ot0[r] += v[0]; ot0[r + 1] += v[1]; ot0[r + 2] += v[2]; ot0[r + 3] += v[3];
          }
        }
    }
  }
  __syncthreads();

  // ---- transpose summed Ot via swizzled Os[64][64], coalesced stores ----
  __bf16* Os = (__bf16*)smem;
  if (shalf == 0) {
    int row = q;
#pragma unroll
    for (int dblk = 0; dblk < 2; ++dblk)
#pragma unroll
      for (int rp = 0; rp < 4; ++rp) {
        int r  = rp * 4;
        int g  = dblk * 4 + rp;
        int by = row * 128 + ((g ^ (row & 7)) * 16) + hh * 8;
        float a0 = dblk ? ot1[r]     : ot0[r];
        float a1 = dblk ? ot1[r + 1] : ot0[r + 1];
        float a2 = dblk ? ot1[r + 2] : ot0[r + 2];
        float a3 = dblk ? ot1[r + 3] : ot0[r + 3];
        unsigned long long val =
            (unsigned long long)pk2(a0, a1) | ((unsigned long long)pk2(a2, a3) << 32);
        *reinterpret_cast<unsigned long long*>((char*)Os + by) = val;
      }
  }
  __syncthreads();
#pragma unroll
  for (int i = 0; i < 2; ++i) {
    int c   = i * 256 + t;
    int row = c >> 3;
    int ch  = c & 7;
    bf16x8 v = *reinterpret_cast<const bf16x8*>(
        (char*)Os + row * 128 + ((ch ^ (row & 7)) * 16));
    *reinterpret_cast<bf16x8*>(&O[((size_t)(b * S) + q0 + row) * E + h * Dh + ch * 8]) = v;
  }
}

extern "C" void kernel_launch(void* const* d_in, const int* in_sizes, int n_in,
                              void* d_out, int out_size, void* d_ws, size_t ws_size,
                              hipStream_t stream) {
  const float* query = (const float*)d_in[0];
  const float* key_  = (const float*)d_in[1];
  const float* value = (const float*)d_in[2];
  const float* Wq    = (const float*)d_in[3];
  const float* Wk    = (const float*)d_in[4];
  const float* Wv    = (const float*)d_in[5];
  const float* Wo    = (const float*)d_in[6];

  char* ws = (char*)d_ws;
  // layout (56 MB): act_q/k/v 24 MB | Wqkv 6 MB | Wob 2 MB | pq 8 | pk 8 | pvt 8
  __bf16* aq   = (__bf16*)(ws);                         // [M,E] bf16
  __bf16* ak   = (__bf16*)(ws + ((size_t)8 << 20));
  __bf16* av   = (__bf16*)(ws + ((size_t)16 << 20));
  __bf16* wqkv = (__bf16*)(ws + ((size_t)24 << 20));    // [3072,1024]
  __bf16* wob  = (__bf16*)(ws + ((size_t)30 << 20));    // [1024,1024]
  __bf16* pq   = (__bf16*)(ws + ((size_t)32 << 20));    // [B,H,S,D]
  __bf16* pk   = (__bf16*)(ws + ((size_t)40 << 20));    // [B,H,S,D]
  __bf16* pvt  = (__bf16*)(ws + ((size_t)48 << 20));    // [B,H,D,S] (s-perm)
  __bf16* ob   = (__bf16*)(ws);                         // [M,E] aliases dead act_q

  convert_bf16<<<dim3(512, 7), 256, 0, stream>>>(query, key_, value, Wq, Wk, Wv,
                                                 Wo, aq, ak, av, wqkv, wob);

  // merged QKV projection: C[4096,3072] over Wqkv, 768 blocks (3/CU)
  gemm_bf16nt<128, 0><<<dim3(3072 / 128, M / 128), 256, 0, stream>>>(
      aq, ak, av, wqkv, pq, pk, pvt);

  // attention: 64-q blocks, 256 threads (4 waves, s-split in block) -> 1024 blocks
  attn_sigmoid<<<dim3(S / 64, H, Bsz), 256, 0, stream>>>(pq, pk, pvt, ob);

  // final GEMM: 64-row tiles -> 512 blocks (2/CU)
  gemm_bf16nt<64, 2><<<dim3(E / 128, M / 64), 256, 0, stream>>>(
      ob, nullptr, nullptr, wob, (float*)d_out, nullptr, nullptr);
}